// Round 1
// baseline (523.523 us; speedup 1.0000x reference)
//
#include <hip/hip_runtime.h>
#include <cstdint>
#include <cstddef>

#define BB 32
#define SS 4096
#define DD 512
#define AA 3
#define KK 4
#define OUTD 512

#define NCHUNK 32
#define ROWS_PER_BLOCK (SS / NCHUNK)   // 128
#define TR 16                          // rows staged per LDS tile
#define NIT (ROWS_PER_BLOCK / TR)      // 8
#define XROW 520                       // padded LDS row stride in floats (520%32=8 -> bank-spread)

// Small-weights LDS layout (sw):
// [0..11]  centers (K*A = 12)
// [12..14] ba (3)
// [15..32] Wh (3*6 = 18)   Wh[a][i] at 15 + a*6 + i
// [33..38] bh (6)
// [39..62] Wk (6*4 = 24)   Wk[i][k] at 39 + i*4 + k
// [63..66] bk (4)
//
// R3 structure: single HBM read of x. 16-row tile staged in LDS; phase A
// computes fw for all 16 rows CONCURRENTLY (16 lanes/row, 4-level xor
// reduce within 16-lane groups -> DPP, no ds_bpermute chains); phase B
// pools from the same LDS tile into per-thread register accumulators
// (2 cols/thread -> acc[4][2], no LDS read-modify-write, no red[] bank
// conflicts). Atomics once per thread at block end.
__global__ __launch_bounds__(256) void fused_pool_kernel(
    const float* __restrict__ x, const float* __restrict__ centers,
    const float* __restrict__ Wa, const float* __restrict__ ba,
    const float* __restrict__ Wh, const float* __restrict__ bh,
    const float* __restrict__ Wk, const float* __restrict__ bk,
    float* __restrict__ pooled)
{
    __shared__ alignas(16) float  xs[TR * XROW];   // 33.3 KB
    __shared__ alignas(16) float  wat[AA * DD];    // 6 KB, Wa transposed: wat[a*512+d]
    __shared__ float  sw[68];
    __shared__ float4 fw_sh[TR];

    const int tid   = threadIdx.x;
    const int b     = blockIdx.y;
    const int chunk = blockIdx.x;

    if (tid < 12)      sw[tid] = centers[tid];
    else if (tid < 15) sw[tid] = ba[tid - 12];
    else if (tid < 33) sw[tid] = Wh[tid - 15];
    else if (tid < 39) sw[tid] = bh[tid - 33];
    else if (tid < 63) sw[tid] = Wk[tid - 39];
    else if (tid < 67) sw[tid] = bk[tid - 63];
    for (int d = tid; d < DD; d += 256) {
        wat[0 * DD + d] = Wa[d * 3 + 0];
        wat[1 * DD + d] = Wa[d * 3 + 1];
        wat[2 * DD + d] = Wa[d * 3 + 2];
    }

    const int g   = tid >> 4;     // row within tile (0..15), 4 groups per wave
    const int l16 = tid & 15;     // lane within 16-lane group
    const int c2  = tid * 2;      // phase-B column pair owned by this thread
    const int s_base = chunk * ROWS_PER_BLOCK;
    const float* xb = x + (size_t)b * SS * DD;

    float2 acc[KK];
    #pragma unroll
    for (int k = 0; k < KK; ++k) { acc[k].x = 0.f; acc[k].y = 0.f; }

    for (int it = 0; it < NIT; ++it) {
        const int s0 = s_base + it * TR;

        // ---- Stage: issue all 8 global float4 loads first (latency overlaps
        //      the barrier), then write to LDS after prev phase B is done ----
        float4 st[8];
        #pragma unroll
        for (int t = 0; t < 8; ++t) {
            const int idx = tid + t * 256;        // 0..2047 float4 slots
            const int row = idx >> 7;             // 128 float4 per row
            const int c4  = (idx & 127) << 2;     // float column
            st[t] = *(const float4*)(xb + (size_t)(s0 + row) * DD + c4);
        }
        __syncthreads();                          // prev phase B done with xs/fw_sh
        #pragma unroll
        for (int t = 0; t < 8; ++t) {
            const int idx = tid + t * 256;
            const int row = idx >> 7;
            const int c4  = (idx & 127) << 2;
            *(float4*)(xs + row * XROW + c4) = st[t];
        }
        __syncthreads();                          // tile visible to phase A

        // ---- Phase A: fw for 16 rows concurrently (16 lanes per row) ----
        {
            const float* xrow = xs + g * XROW;
            float p0 = 0.f, p1 = 0.f, p2 = 0.f;
            #pragma unroll
            for (int i = 0; i < 8; ++i) {
                const int c = l16 * 4 + i * 64;
                float4 v  = *(const float4*)(xrow + c);
                float4 w0 = *(const float4*)(wat + c);            // broadcast across groups
                float4 w1 = *(const float4*)(wat + DD + c);
                float4 w2 = *(const float4*)(wat + 2 * DD + c);
                p0 += v.x * w0.x + v.y * w0.y + v.z * w0.z + v.w * w0.w;
                p1 += v.x * w1.x + v.y * w1.y + v.z * w1.z + v.w * w1.w;
                p2 += v.x * w2.x + v.y * w2.y + v.z * w2.z + v.w * w2.w;
            }
            #pragma unroll
            for (int off = 8; off >= 1; off >>= 1) {  // within-16 xor: DPP, short chain
                p0 += __shfl_xor(p0, off);
                p1 += __shfl_xor(p1, off);
                p2 += __shfl_xor(p2, off);
            }
            const float af0 = p0 + sw[12];
            const float af1 = p1 + sw[13];
            const float af2 = p2 + sw[14];

            float dist[KK];
            #pragma unroll
            for (int k = 0; k < KK; ++k) {
                float da = af0 - sw[k * 3 + 0];
                float db = af1 - sw[k * 3 + 1];
                float dc = af2 - sw[k * 3 + 2];
                dist[k] = sqrtf(da * da + db * db + dc * dc);
            }
            float mn = fminf(fminf(dist[0], dist[1]), fminf(dist[2], dist[3]));
            float e[KK]; float esum = 0.f;
            #pragma unroll
            for (int k = 0; k < KK; ++k) { e[k] = __expf(mn - dist[k]); esum += e[k]; }
            const float einv = 1.0f / esum;

            float h[6];
            #pragma unroll
            for (int i6 = 0; i6 < 6; ++i6) {
                float v = af0 * sw[15 + i6] + af1 * sw[21 + i6]
                        + af2 * sw[27 + i6] + sw[33 + i6];
                h[i6] = fmaxf(v, 0.0f);
            }
            float logit[KK];
            #pragma unroll
            for (int k = 0; k < KK; ++k) {
                float v = sw[63 + k];
                #pragma unroll
                for (int i6 = 0; i6 < 6; ++i6) v += h[i6] * sw[39 + i6 * 4 + k];
                logit[k] = v + e[k] * einv;
            }
            float mx = fmaxf(fmaxf(logit[0], logit[1]), fmaxf(logit[2], logit[3]));
            float f0 = __expf(logit[0] - mx), f1 = __expf(logit[1] - mx);
            float f2 = __expf(logit[2] - mx), f3 = __expf(logit[3] - mx);
            const float finv = 1.0f / (f0 + f1 + f2 + f3);
            if (l16 == 0)
                fw_sh[g] = make_float4(f0 * finv, f1 * finv, f2 * finv, f3 * finv);
        }
        __syncthreads();                          // fw_sh visible to phase B

        // ---- Phase B: pool tile into register accumulators (2 cols/thread) ----
        #pragma unroll
        for (int r = 0; r < TR; ++r) {
            float2 xv = *(const float2*)(xs + r * XROW + c2);
            float4 f  = fw_sh[r];                 // same-address broadcast
            acc[0].x += f.x * xv.x; acc[0].y += f.x * xv.y;
            acc[1].x += f.y * xv.x; acc[1].y += f.y * xv.y;
            acc[2].x += f.z * xv.x; acc[2].y += f.z * xv.y;
            acc[3].x += f.w * xv.x; acc[3].y += f.w * xv.y;
        }
    }

    // one atomic flush per thread: pooled[b][k*512 + c2 .. c2+1]
    float* pb = pooled + (size_t)b * (KK * DD);
    #pragma unroll
    for (int k = 0; k < KK; ++k) {
        unsafeAtomicAdd(&pb[k * DD + c2],     acc[k].x);
        unsafeAtomicAdd(&pb[k * DD + c2 + 1], acc[k].y);
    }
}

// out[b][col] = bout[col] + sum_j pooled[b][j] * Wout[j][col]
// grid: (colchunk 2, b 32, jchunk 16), block 256  (kept from R2)
__global__ __launch_bounds__(256) void out_gemm_kernel(
    const float* __restrict__ pooled, const float* __restrict__ Wout,
    const float* __restrict__ bout, float* __restrict__ out)
{
    __shared__ float p_sh[128];
    const int tid = threadIdx.x;
    const int cc = blockIdx.x, b = blockIdx.y, jc = blockIdx.z;

    if (tid < 128) p_sh[tid] = pooled[b * 2048 + jc * 128 + tid];
    __syncthreads();

    const int col = cc * 256 + tid;
    const float* wp = Wout + (size_t)(jc * 128) * OUTD + col;
    float acc = 0.f;
    #pragma unroll 8
    for (int jj = 0; jj < 128; ++jj) {
        acc += p_sh[jj] * wp[(size_t)jj * OUTD];
    }
    if (jc == 0) acc += bout[col];
    unsafeAtomicAdd(&out[b * OUTD + col], acc);
}

extern "C" void kernel_launch(void* const* d_in, const int* in_sizes, int n_in,
                              void* d_out, int out_size, void* d_ws, size_t ws_size,
                              hipStream_t stream) {
    (void)in_sizes; (void)n_in; (void)out_size; (void)ws_size;
    const float* x       = (const float*)d_in[0];
    const float* centers = (const float*)d_in[1];
    const float* Wa      = (const float*)d_in[2];
    const float* ba      = (const float*)d_in[3];
    const float* Wh      = (const float*)d_in[4];
    const float* bh      = (const float*)d_in[5];
    const float* Wk      = (const float*)d_in[6];
    const float* bk      = (const float*)d_in[7];
    const float* Wout    = (const float*)d_in[8];
    const float* bout    = (const float*)d_in[9];
    float* out    = (float*)d_out;
    float* pooled = (float*)d_ws;   // B*K*D floats = 256 KB

    hipMemsetAsync(pooled, 0, (size_t)BB * KK * DD * sizeof(float), stream);
    hipMemsetAsync(out, 0, (size_t)BB * OUTD * sizeof(float), stream);

    fused_pool_kernel<<<dim3(NCHUNK, BB), 256, 0, stream>>>(
        x, centers, Wa, ba, Wh, bh, Wk, bk, pooled);
    out_gemm_kernel<<<dim3(2, BB, 16), 256, 0, stream>>>(pooled, Wout, bout, out);
}

// Round 2
// 515.982 us; speedup vs baseline: 1.0146x; 1.0146x over previous
//
#include <hip/hip_runtime.h>
#include <cstdint>
#include <cstddef>

#define BB 32
#define SS 4096
#define DD 512
#define AA 3
#define KK 4
#define OUTD 512

#define TR 16                          // rows staged per LDS tile
#define XROW 520                       // padded LDS row stride in floats

// Small-weights LDS layout (sw):
// [0..11]  centers (K*A = 12)
// [12..14] ba (3)
// [15..32] Wh (3*6 = 18)   Wh[a][i] at 15 + a*6 + i
// [33..38] bh (6)
// [39..62] Wk (6*4 = 24)   Wk[i][k] at 39 + i*4 + k
// [63..66] bk (4)
//
// R4 structure:
//  - NO atomics anywhere: each block writes partial[b][chunk][2048] (plain
//    coalesced stores, 8 MB ws); chunk-reduce folded into out kernel.
//    R3 counters showed 231 MiB HBM WRITE from 2M atomic line-RMWs vs
//    256 KB unique data.
//  - T14 async-stage: next tile's 8 global float4 loads issued right after
//    the current tile's LDS write, in flight across phases A+B (R3 issued
//    them right before the consuming barrier -> full HBM latency exposed
//    every iteration; VALUBusy 12%, hbm 24%, latency-bound).
__device__ __forceinline__ void load_tile(const float* __restrict__ xb,
                                          int s0, int tid, float4 st[8]) {
    #pragma unroll
    for (int t = 0; t < 8; ++t) {
        const int idx = tid + t * 256;        // 0..2047 float4 slots
        const int row = idx >> 7;             // 128 float4 per row
        const int c4  = (idx & 127) << 2;     // float column
        st[t] = *(const float4*)(xb + (size_t)(s0 + row) * DD + c4);
    }
}

__global__ __launch_bounds__(256) void fused_pool_kernel(
    const float* __restrict__ x, const float* __restrict__ centers,
    const float* __restrict__ Wa, const float* __restrict__ ba,
    const float* __restrict__ Wh, const float* __restrict__ bh,
    const float* __restrict__ Wk, const float* __restrict__ bk,
    float* __restrict__ partial)
{
    __shared__ alignas(16) float  xs[TR * XROW];   // 33.3 KB
    __shared__ alignas(16) float  wat[AA * DD];    // 6 KB, Wa transposed
    __shared__ float  sw[68];
    __shared__ float4 fw_sh[TR];

    const int tid   = threadIdx.x;
    const int b     = blockIdx.y;
    const int chunk = blockIdx.x;
    const int nch   = gridDim.x;
    const int rows_per_block = SS / nch;
    const int nit   = rows_per_block / TR;

    if (tid < 12)      sw[tid] = centers[tid];
    else if (tid < 15) sw[tid] = ba[tid - 12];
    else if (tid < 33) sw[tid] = Wh[tid - 15];
    else if (tid < 39) sw[tid] = bh[tid - 33];
    else if (tid < 63) sw[tid] = Wk[tid - 39];
    else if (tid < 67) sw[tid] = bk[tid - 63];
    for (int d = tid; d < DD; d += 256) {
        wat[0 * DD + d] = Wa[d * 3 + 0];
        wat[1 * DD + d] = Wa[d * 3 + 1];
        wat[2 * DD + d] = Wa[d * 3 + 2];
    }

    const int g   = tid >> 4;     // row within tile (0..15)
    const int l16 = tid & 15;     // lane within 16-lane group
    const int c2  = tid * 2;      // column pair owned in phase B
    const int s_base = chunk * rows_per_block;
    const float* xb = x + (size_t)b * SS * DD;

    float2 acc[KK];
    #pragma unroll
    for (int k = 0; k < KK; ++k) { acc[k].x = 0.f; acc[k].y = 0.f; }

    float4 st[8];
    load_tile(xb, s_base, tid, st);               // prologue: tile 0 in flight

    #pragma unroll 1
    for (int it = 0; it < nit; ++it) {
        __syncthreads();                          // xs free (prev phase B done)
        #pragma unroll
        for (int t = 0; t < 8; ++t) {
            const int idx = tid + t * 256;
            *(float4*)(xs + (idx >> 7) * XROW + ((idx & 127) << 2)) = st[t];
        }
        if (it + 1 < nit)                         // prefetch next tile: in flight
            load_tile(xb, s_base + (it + 1) * TR, tid, st);   // across A + B
        __syncthreads();                          // tile visible to phase A

        // ---- Phase A: fw for 16 rows concurrently (16 lanes per row) ----
        {
            const float* xrow = xs + g * XROW;
            float p0 = 0.f, p1 = 0.f, p2 = 0.f;
            #pragma unroll
            for (int i = 0; i < 8; ++i) {
                const int c = l16 * 4 + i * 64;
                float4 v  = *(const float4*)(xrow + c);
                float4 w0 = *(const float4*)(wat + c);
                float4 w1 = *(const float4*)(wat + DD + c);
                float4 w2 = *(const float4*)(wat + 2 * DD + c);
                p0 += v.x * w0.x + v.y * w0.y + v.z * w0.z + v.w * w0.w;
                p1 += v.x * w1.x + v.y * w1.y + v.z * w1.z + v.w * w1.w;
                p2 += v.x * w2.x + v.y * w2.y + v.z * w2.z + v.w * w2.w;
            }
            #pragma unroll
            for (int off = 8; off >= 1; off >>= 1) {
                p0 += __shfl_xor(p0, off);
                p1 += __shfl_xor(p1, off);
                p2 += __shfl_xor(p2, off);
            }
            const float af0 = p0 + sw[12];
            const float af1 = p1 + sw[13];
            const float af2 = p2 + sw[14];

            float dist[KK];
            #pragma unroll
            for (int k = 0; k < KK; ++k) {
                float da = af0 - sw[k * 3 + 0];
                float db = af1 - sw[k * 3 + 1];
                float dc = af2 - sw[k * 3 + 2];
                dist[k] = sqrtf(da * da + db * db + dc * dc);
            }
            float mn = fminf(fminf(dist[0], dist[1]), fminf(dist[2], dist[3]));
            float e[KK]; float esum = 0.f;
            #pragma unroll
            for (int k = 0; k < KK; ++k) { e[k] = __expf(mn - dist[k]); esum += e[k]; }
            const float einv = 1.0f / esum;

            float h[6];
            #pragma unroll
            for (int i6 = 0; i6 < 6; ++i6) {
                float v = af0 * sw[15 + i6] + af1 * sw[21 + i6]
                        + af2 * sw[27 + i6] + sw[33 + i6];
                h[i6] = fmaxf(v, 0.0f);
            }
            float logit[KK];
            #pragma unroll
            for (int k = 0; k < KK; ++k) {
                float v = sw[63 + k];
                #pragma unroll
                for (int i6 = 0; i6 < 6; ++i6) v += h[i6] * sw[39 + i6 * 4 + k];
                logit[k] = v + e[k] * einv;
            }
            float mx = fmaxf(fmaxf(logit[0], logit[1]), fmaxf(logit[2], logit[3]));
            float f0 = __expf(logit[0] - mx), f1 = __expf(logit[1] - mx);
            float f2 = __expf(logit[2] - mx), f3 = __expf(logit[3] - mx);
            const float finv = 1.0f / (f0 + f1 + f2 + f3);
            if (l16 == 0)
                fw_sh[g] = make_float4(f0 * finv, f1 * finv, f2 * finv, f3 * finv);
        }
        __syncthreads();                          // fw_sh visible to phase B

        // ---- Phase B: pool tile into register accumulators (2 cols/thread) ----
        #pragma unroll
        for (int r = 0; r < TR; ++r) {
            float2 xv = *(const float2*)(xs + r * XROW + c2);
            float4 f  = fw_sh[r];                 // same-address broadcast
            acc[0].x += f.x * xv.x; acc[0].y += f.x * xv.y;
            acc[1].x += f.y * xv.x; acc[1].y += f.y * xv.y;
            acc[2].x += f.z * xv.x; acc[2].y += f.z * xv.y;
            acc[3].x += f.w * xv.x; acc[3].y += f.w * xv.y;
        }
    }

    // plain coalesced partial store: partial[b][chunk][k*512 + c2..c2+1]
    float* pp = partial + ((size_t)b * nch + chunk) * (KK * DD);
    #pragma unroll
    for (int k = 0; k < KK; ++k)
        *(float2*)(pp + k * DD + c2) = acc[k];
}

// out[b][col] = bout[col] + sum_j (sum_c partial[b][c][j]) * Wout[j][col]
// grid (2 cc, 32 b), block 256. No atomics, no memset.
__global__ __launch_bounds__(256) void out_gemm_kernel(
    const float* __restrict__ partial, const float* __restrict__ Wout,
    const float* __restrict__ bout, float* __restrict__ out, int nch)
{
    __shared__ float  p_sh[2048];                 // 8 KB
    __shared__ float4 red4[4][64];                // 4 KB jslice combine
    const int tid = threadIdx.x;
    const int cc = blockIdx.x, b = blockIdx.y;

    // chunk-reduce into p_sh (coalesced: consecutive tid -> consecutive j)
    for (int j = tid; j < 2048; j += 256) {
        const float* pj = partial + (size_t)b * nch * 2048 + j;
        float s = 0.f;
        for (int c = 0; c < nch; ++c) s += pj[(size_t)c * 2048];
        p_sh[j] = s;
    }
    __syncthreads();

    // thread = (jslice 0..3) x (col-quad 0..63); float4 Wout reads, 1KB/wave/j
    const int q  = tid & 63;
    const int js = tid >> 6;
    const int colbase = cc * 256 + q * 4;
    const float* wp = Wout + (size_t)(js * 512) * OUTD + colbase;
    float4 a = make_float4(0.f, 0.f, 0.f, 0.f);
    #pragma unroll 8
    for (int j = 0; j < 512; ++j) {
        float4 w = *(const float4*)(wp + (size_t)j * OUTD);
        float  p = p_sh[js * 512 + j];            // wave-uniform broadcast
        a.x += p * w.x; a.y += p * w.y; a.z += p * w.z; a.w += p * w.w;
    }
    red4[js][q] = a;
    __syncthreads();

    const int qq = tid >> 2, e = tid & 3;         // col = cc*256 + tid
    float s = 0.f;
    #pragma unroll
    for (int s4 = 0; s4 < 4; ++s4)
        s += ((const float*)&red4[s4][qq])[e];
    out[b * OUTD + cc * 256 + tid] = s + bout[cc * 256 + tid];
}

extern "C" void kernel_launch(void* const* d_in, const int* in_sizes, int n_in,
                              void* d_out, int out_size, void* d_ws, size_t ws_size,
                              hipStream_t stream) {
    (void)in_sizes; (void)n_in; (void)out_size;
    const float* x       = (const float*)d_in[0];
    const float* centers = (const float*)d_in[1];
    const float* Wa      = (const float*)d_in[2];
    const float* ba      = (const float*)d_in[3];
    const float* Wh      = (const float*)d_in[4];
    const float* bh      = (const float*)d_in[5];
    const float* Wk      = (const float*)d_in[6];
    const float* bk      = (const float*)d_in[7];
    const float* Wout    = (const float*)d_in[8];
    const float* bout    = (const float*)d_in[9];
    float* out     = (float*)d_out;
    float* partial = (float*)d_ws;

    // partial needs B * nch * 2048 floats; halve nch until it fits (nch=32 -> 8 MB)
    int nch = 32;
    while (nch > 1 && (size_t)BB * nch * 2048 * sizeof(float) > ws_size) nch >>= 1;

    fused_pool_kernel<<<dim3(nch, BB), 256, 0, stream>>>(
        x, centers, Wa, ba, Wh, bh, Wk, bk, partial);
    out_gemm_kernel<<<dim3(2, BB), 256, 0, stream>>>(partial, Wout, bout, out, nch);
}

// Round 3
// 413.561 us; speedup vs baseline: 1.2659x; 1.2477x over previous
//
#include <hip/hip_runtime.h>
#include <cstdint>
#include <cstddef>

#define BB 32
#define SS 4096
#define DD 512
#define AA 3
#define KK 4
#define OUTD 512

#define NCH 32                         // compile-time chunk count (ws = 8 MB << 1 GiB)
#define ROWS_PER_BLOCK (SS / NCH)      // 128
#define TR 16                          // rows staged per LDS tile
#define NIT (ROWS_PER_BLOCK / TR)      // 8
#define XROW 520                       // padded LDS row stride in floats

// Small-weights LDS layout (sw):
// [0..11]  centers (K*A = 12)
// [12..14] ba (3)
// [15..32] Wh (3*6 = 18)
// [33..38] bh (6)
// [39..62] Wk (6*4 = 24)
// [63..66] bk (4)
//
// R5 structure (on top of R4's no-atomics + T14 prefetch):
//  - Phase B is PURE REGISTER FMA: the prefetch regs already hold the
//    current tile in phase-B ownership order (thread: rows (tid>>7)+2t,
//    cols (tid&127)*4..+3). No xs re-read, and xs is dead after phase A
//    -> top-of-loop barrier deleted (2 barriers/tile, was 3). Phase B
//    overlaps next tile's LDS write + prefetch issue.
//  - Ping-pong stA/stB so tile t stays live for phase B while t+1 loads.
//  - Cross-half combine at end (tid and tid+128 share columns, differ in
//    row parity) via xs scratch.
__device__ __forceinline__ void load_tile(const float* __restrict__ xb,
                                          int s0, int tid, float4 st[8]) {
    #pragma unroll
    for (int t = 0; t < 8; ++t) {
        const int idx = tid + t * 256;
        const int row = idx >> 7;             // (tid>>7) + 2t
        const int c4  = (idx & 127) << 2;     // (tid&127)*4, invariant in t
        st[t] = *(const float4*)(xb + (size_t)(s0 + row) * DD + c4);
    }
}

__global__ __launch_bounds__(256) void fused_pool_kernel(
    const float* __restrict__ x, const float* __restrict__ centers,
    const float* __restrict__ Wa, const float* __restrict__ ba,
    const float* __restrict__ Wh, const float* __restrict__ bh,
    const float* __restrict__ Wk, const float* __restrict__ bk,
    float* __restrict__ partial)
{
    __shared__ alignas(16) float  xs[TR * XROW];   // 33.3 KB (phase-A only + end scratch)
    __shared__ alignas(16) float  wat[AA * DD];    // 6 KB, Wa transposed
    __shared__ float  sw[68];
    __shared__ float4 fw_sh[TR];

    const int tid   = threadIdx.x;
    const int b     = blockIdx.y;
    const int chunk = blockIdx.x;

    if (tid < 12)      sw[tid] = centers[tid];
    else if (tid < 15) sw[tid] = ba[tid - 12];
    else if (tid < 33) sw[tid] = Wh[tid - 15];
    else if (tid < 39) sw[tid] = bh[tid - 33];
    else if (tid < 63) sw[tid] = Wk[tid - 39];
    else if (tid < 67) sw[tid] = bk[tid - 63];
    for (int d = tid; d < DD; d += 256) {
        wat[0 * DD + d] = Wa[d * 3 + 0];
        wat[1 * DD + d] = Wa[d * 3 + 1];
        wat[2 * DD + d] = Wa[d * 3 + 2];
    }

    const int g    = tid >> 4;     // phase-A row (0..15)
    const int l16  = tid & 15;
    const int half = tid >> 7;     // row parity owned in phase B
    const int c4   = (tid & 127) << 2;
    const int s_base = chunk * ROWS_PER_BLOCK;
    const float* xb = x + (size_t)b * SS * DD;

    float4 acc0 = {0,0,0,0}, acc1 = {0,0,0,0}, acc2 = {0,0,0,0}, acc3 = {0,0,0,0};

    float4 stA[8], stB[8];
    load_tile(xb, s_base, tid, stA);

    auto step = [&](float4 (&cur)[8], float4 (&nxt)[8], int it) {
        // write current tile to xs (xs is free: previous phase A done)
        #pragma unroll
        for (int t = 0; t < 8; ++t)
            *(float4*)(xs + (half + 2 * t) * XROW + c4) = cur[t];
        if (it + 1 < NIT)
            load_tile(xb, s_base + (it + 1) * TR, tid, nxt);  // in flight across A+B
        __syncthreads();                          // xs ready (and wat/sw on it==0)

        // ---- Phase A: fw for 16 rows concurrently (16 lanes per row) ----
        {
            const float* xrow = xs + g * XROW;
            float p0 = 0.f, p1 = 0.f, p2 = 0.f;
            #pragma unroll
            for (int i = 0; i < 8; ++i) {
                const int c = l16 * 4 + i * 64;
                float4 v  = *(const float4*)(xrow + c);
                float4 w0 = *(const float4*)(wat + c);            // broadcast
                float4 w1 = *(const float4*)(wat + DD + c);
                float4 w2 = *(const float4*)(wat + 2 * DD + c);
                p0 += v.x * w0.x + v.y * w0.y + v.z * w0.z + v.w * w0.w;
                p1 += v.x * w1.x + v.y * w1.y + v.z * w1.z + v.w * w1.w;
                p2 += v.x * w2.x + v.y * w2.y + v.z * w2.z + v.w * w2.w;
            }
            #pragma unroll
            for (int off = 8; off >= 1; off >>= 1) {
                p0 += __shfl_xor(p0, off);
                p1 += __shfl_xor(p1, off);
                p2 += __shfl_xor(p2, off);
            }
            const float af0 = p0 + sw[12];
            const float af1 = p1 + sw[13];
            const float af2 = p2 + sw[14];

            float dist[KK];
            #pragma unroll
            for (int k = 0; k < KK; ++k) {
                float da = af0 - sw[k * 3 + 0];
                float db = af1 - sw[k * 3 + 1];
                float dc = af2 - sw[k * 3 + 2];
                dist[k] = sqrtf(da * da + db * db + dc * dc);
            }
            float mn = fminf(fminf(dist[0], dist[1]), fminf(dist[2], dist[3]));
            float e[KK]; float esum = 0.f;
            #pragma unroll
            for (int k = 0; k < KK; ++k) { e[k] = __expf(mn - dist[k]); esum += e[k]; }
            const float einv = 1.0f / esum;

            float h[6];
            #pragma unroll
            for (int i6 = 0; i6 < 6; ++i6) {
                float v = af0 * sw[15 + i6] + af1 * sw[21 + i6]
                        + af2 * sw[27 + i6] + sw[33 + i6];
                h[i6] = fmaxf(v, 0.0f);
            }
            float logit[KK];
            #pragma unroll
            for (int k = 0; k < KK; ++k) {
                float v = sw[63 + k];
                #pragma unroll
                for (int i6 = 0; i6 < 6; ++i6) v += h[i6] * sw[39 + i6 * 4 + k];
                logit[k] = v + e[k] * einv;
            }
            float mx = fmaxf(fmaxf(logit[0], logit[1]), fmaxf(logit[2], logit[3]));
            float f0 = __expf(logit[0] - mx), f1 = __expf(logit[1] - mx);
            float f2 = __expf(logit[2] - mx), f3 = __expf(logit[3] - mx);
            const float finv = 1.0f / (f0 + f1 + f2 + f3);
            if (l16 == 0)
                fw_sh[g] = make_float4(f0 * finv, f1 * finv, f2 * finv, f3 * finv);
        }
        __syncthreads();                          // fw ready + xs consumed

        // ---- Phase B: pure register FMA from cur[] ----
        #pragma unroll
        for (int t = 0; t < 8; ++t) {
            float4 v = cur[t];
            float4 f = fw_sh[half + 2 * t];       // same-address broadcast per wave
            acc0.x += f.x * v.x; acc0.y += f.x * v.y; acc0.z += f.x * v.z; acc0.w += f.x * v.w;
            acc1.x += f.y * v.x; acc1.y += f.y * v.y; acc1.z += f.y * v.z; acc1.w += f.y * v.w;
            acc2.x += f.z * v.x; acc2.y += f.z * v.y; acc2.z += f.z * v.z; acc2.w += f.z * v.w;
            acc3.x += f.w * v.x; acc3.y += f.w * v.y; acc3.z += f.w * v.z; acc3.w += f.w * v.w;
        }
    };

    #pragma unroll 1
    for (int it = 0; it < NIT; it += 2) {
        step(stA, stB, it);
        step(stB, stA, it + 1);
    }

    // ---- combine thread halves (same cols, different row parity) ----
    __syncthreads();                              // all phase B done; xs free
    float4* red = (float4*)xs;                    // 128 threads * 4 float4 = 8 KB
    if (half == 1) {
        red[(tid - 128) * 4 + 0] = acc0;
        red[(tid - 128) * 4 + 1] = acc1;
        red[(tid - 128) * 4 + 2] = acc2;
        red[(tid - 128) * 4 + 3] = acc3;
    }
    __syncthreads();
    if (half == 0) {
        float4 o0 = red[tid * 4 + 0], o1 = red[tid * 4 + 1];
        float4 o2 = red[tid * 4 + 2], o3 = red[tid * 4 + 3];
        acc0.x += o0.x; acc0.y += o0.y; acc0.z += o0.z; acc0.w += o0.w;
        acc1.x += o1.x; acc1.y += o1.y; acc1.z += o1.z; acc1.w += o1.w;
        acc2.x += o2.x; acc2.y += o2.y; acc2.z += o2.z; acc2.w += o2.w;
        acc3.x += o3.x; acc3.y += o3.y; acc3.z += o3.z; acc3.w += o3.w;
        float* pp = partial + ((size_t)b * NCH + chunk) * (KK * DD);
        *(float4*)(pp + 0 * DD + c4) = acc0;
        *(float4*)(pp + 1 * DD + c4) = acc1;
        *(float4*)(pp + 2 * DD + c4) = acc2;
        *(float4*)(pp + 3 * DD + c4) = acc3;
    }
}

// out[b][col] = bout[col] + sum_j (sum_c partial[b][c][j]) * Wout[j][col]
// grid (4 cc, 32 b), block 256. Compile-time NCH chunk-reduce with float4+ILP.
__global__ __launch_bounds__(256) void out_gemm_kernel(
    const float* __restrict__ partial, const float* __restrict__ Wout,
    const float* __restrict__ bout, float* __restrict__ out)
{
    __shared__ float  p_sh[2048];                 // 8 KB
    __shared__ float4 red4[8][32];                // 4 KB
    const int tid = threadIdx.x;
    const int cc = blockIdx.x, b = blockIdx.y;

    // chunk-reduce into p_sh: 512 float4 slots, 2 per thread
    {
        const float4* pbase = (const float4*)(partial + (size_t)b * NCH * 2048);
        #pragma unroll
        for (int s = 0; s < 2; ++s) {
            const int slot = tid + s * 256;
            float4 a = {0,0,0,0};
            #pragma unroll 4
            for (int c = 0; c < NCH; ++c) {
                float4 v = pbase[(size_t)c * 512 + slot];
                a.x += v.x; a.y += v.y; a.z += v.z; a.w += v.w;
            }
            *(float4*)(p_sh + slot * 4) = a;
        }
    }
    __syncthreads();

    // thread = (jslice 0..7) x (col-quad 0..31): 128 cols per block
    const int q  = tid & 31;
    const int js = tid >> 5;
    const int colbase = cc * 128 + q * 4;
    const float* wp = Wout + (size_t)(js * 256) * OUTD + colbase;
    float4 a = {0,0,0,0};
    #pragma unroll 8
    for (int j = 0; j < 256; ++j) {
        float4 w = *(const float4*)(wp + (size_t)j * OUTD);
        float  p = p_sh[js * 256 + j];            // broadcast (2 addrs/wave)
        a.x += p * w.x; a.y += p * w.y; a.z += p * w.z; a.w += p * w.w;
    }
    red4[js][q] = a;
    __syncthreads();

    if (tid < 128) {
        const int qq = tid >> 2, e = tid & 3;
        float s = 0.f;
        #pragma unroll
        for (int s8 = 0; s8 < 8; ++s8)
            s += ((const float*)&red4[s8][qq])[e];
        const int col = cc * 128 + tid;
        out[b * OUTD + col] = s + bout[col];
    }
}

extern "C" void kernel_launch(void* const* d_in, const int* in_sizes, int n_in,
                              void* d_out, int out_size, void* d_ws, size_t ws_size,
                              hipStream_t stream) {
    (void)in_sizes; (void)n_in; (void)out_size; (void)ws_size;
    const float* x       = (const float*)d_in[0];
    const float* centers = (const float*)d_in[1];
    const float* Wa      = (const float*)d_in[2];
    const float* ba      = (const float*)d_in[3];
    const float* Wh      = (const float*)d_in[4];
    const float* bh      = (const float*)d_in[5];
    const float* Wk      = (const float*)d_in[6];
    const float* bk      = (const float*)d_in[7];
    const float* Wout    = (const float*)d_in[8];
    const float* bout    = (const float*)d_in[9];
    float* out     = (float*)d_out;
    float* partial = (float*)d_ws;   // B * NCH * 2048 floats = 8 MB (ws is 1 GiB)

    fused_pool_kernel<<<dim3(NCH, BB), 256, 0, stream>>>(
        x, centers, Wa, ba, Wh, bh, Wk, bk, partial);
    out_gemm_kernel<<<dim3(4, BB), 256, 0, stream>>>(partial, Wout, bout, out);
}